// Round 1
// baseline (507381.152 us; speedup 1.0000x reference)
//
#include <hip/hip_runtime.h>
#include <hip/hip_cooperative_groups.h>

namespace cg = cooperative_groups;

#define T_STEPS 8192
#define DD 1024
#define HH 1024
#define NWG 256      // one persistent WG per CU; each owns 4 h-elements
#define NTHR 512     // 8 waves; thread = seg*16 + col (32 segs x 16 cols)

// Persistent LSTM scan. WG g owns h indices [4g, 4g+4). Each WG computes its
// 16 z-columns (4 gates x 4 h) as dots of length 2048 over [x_t ; h_{t-1}],
// with the needed W_lstm columns held in registers (64 VGPR/thread).
__global__ __launch_bounds__(NTHR, 1) void lstm_scan(
    const float* __restrict__ x, const float* __restrict__ c_in,
    const float* __restrict__ h_in, const float* __restrict__ W,
    const float* __restrict__ b, float* __restrict__ Hh,  // [T+1][H] history
    float* __restrict__ out_tail)                         // c_last | h_last
{
  const int g   = blockIdx.x;
  const int tid = threadIdx.x;
  const int col = tid & 15;   // which of the WG's 16 z-columns
  const int seg = tid >> 4;   // which 64-row segment of the 2048-dot
  const int gate = col >> 2;  // 0=i 1=j 2=f 3=o (order of jnp.split)
  const int hi   = col & 3;
  const int col_global = gate * HH + g * 4 + hi;

  // Load this thread's 64 weights (one-time, ~32 MB across the grid).
  float w[64];
  #pragma unroll
  for (int i = 0; i < 64; ++i)
    w[i] = W[(size_t)(seg * 64 + i) * (4 * HH) + col_global];

  __shared__ float xh[DD + HH];     // [x_t ; h_{t-1}]
  __shared__ float partial[8][16];  // per-wave partials per column
  __shared__ float zbuf[16];
  __shared__ float c_lds[4];

  if (tid < 4) {
    c_lds[tid] = c_in[g * 4 + tid];
    Hh[g * 4 + tid] = h_in[g * 4 + tid];  // history row 0 = h_in
  }
  cg::grid_group grid = cg::this_grid();
  __threadfence();
  grid.sync();

  const int wave = tid >> 6;
  const int lane = tid & 63;

  for (int step = 0; step < T_STEPS; ++step) {
    // Stage x_t and h_{t-1} into LDS (coalesced, 2 floats each per thread).
    #pragma unroll
    for (int r = 0; r < 2; ++r) {
      const int k = tid + r * NTHR;
      xh[k]      = x[(size_t)step * DD + k];
      xh[DD + k] = Hh[(size_t)step * HH + k];
    }
    __syncthreads();

    // 64-FMA dot segment against register weights (LDS reads broadcast
    // across the 16 lanes sharing a seg).
    float p = 0.f;
    #pragma unroll
    for (int i = 0; i < 64; ++i)
      p = fmaf(xh[seg * 64 + i], w[i], p);

    // Reduce over the wave's 4 segs (lane = (seg&3)*16 + col).
    p += __shfl_xor(p, 16);
    p += __shfl_xor(p, 32);
    if (lane < 16) partial[wave][lane] = p;
    __syncthreads();

    // Sum the 8 per-wave partials -> 16 z values.
    if (tid < 16) {
      float z = b[(tid >> 2) * HH + g * 4 + (tid & 3)];
      #pragma unroll
      for (int wv = 0; wv < 8; ++wv) z += partial[wv][tid];
      zbuf[tid] = z;
    }
    __syncthreads();

    // Gates for the WG's 4 h-elements.
    if (tid < 4) {
      const float zi = zbuf[tid], zj = zbuf[4 + tid];
      const float zf = zbuf[8 + tid], zo = zbuf[12 + tid];
      const float fg = 1.f / (1.f + __expf(-(zf + 1.0f)));  // FORGET_BIAS
      const float ig = 1.f / (1.f + __expf(-zi));
      const float nc = c_lds[tid] * fg + ig * tanhf(zj);
      const float nh = tanhf(nc) * (1.f / (1.f + __expf(-zo)));
      c_lds[tid] = nc;
      Hh[(size_t)(step + 1) * HH + g * 4 + tid] = nh;
    }
    __threadfence();
    grid.sync();
  }

  if (tid < 4) {
    out_tail[g * 4 + tid]      = c_lds[tid];                               // c_last
    out_tail[HH + g * 4 + tid] = Hh[(size_t)T_STEPS * HH + g * 4 + tid];   // h_last
  }
}

// output = hs @ W_out + b_out. Simple fp32 tiled GEMM, 64x64 tile, 4x4/thread.
#define BM 64
#define BN 64
#define BK 16
__global__ __launch_bounds__(256, 2) void out_gemm(
    const float* __restrict__ A,    // hs [8192][1024]
    const float* __restrict__ Bw,   // W_out [1024][1024]
    const float* __restrict__ bias,
    float* __restrict__ C)          // [8192][1024]
{
  __shared__ float As[BM][BK];
  __shared__ float Bs[BK][BN];
  const int tid = threadIdx.x;
  const int row0 = blockIdx.y * BM, col0 = blockIdx.x * BN;
  const int tx = tid & 15, ty = tid >> 4;

  float acc[4][4];
  #pragma unroll
  for (int j = 0; j < 4; ++j) {
    const float bv = bias[col0 + tx * 4 + j];
    #pragma unroll
    for (int i = 0; i < 4; ++i) acc[i][j] = bv;
  }

  for (int k0 = 0; k0 < HH; k0 += BK) {
    {
      const int r = tid >> 2, c = (tid & 3) * 4;
      const float4 va = *(const float4*)&A[(size_t)(row0 + r) * HH + k0 + c];
      As[r][c] = va.x; As[r][c + 1] = va.y; As[r][c + 2] = va.z; As[r][c + 3] = va.w;
      const int rb = tid >> 4, cb = (tid & 15) * 4;
      *(float4*)&Bs[rb][cb] = *(const float4*)&Bw[(size_t)(k0 + rb) * HH + col0 + cb];
    }
    __syncthreads();
    #pragma unroll
    for (int kk = 0; kk < BK; ++kk) {
      float a[4], bv[4];
      #pragma unroll
      for (int i = 0; i < 4; ++i) a[i] = As[ty * 4 + i][kk];
      #pragma unroll
      for (int j = 0; j < 4; ++j) bv[j] = Bs[kk][tx * 4 + j];
      #pragma unroll
      for (int i = 0; i < 4; ++i)
        #pragma unroll
        for (int j = 0; j < 4; ++j)
          acc[i][j] = fmaf(a[i], bv[j], acc[i][j]);
    }
    __syncthreads();
  }

  #pragma unroll
  for (int i = 0; i < 4; ++i) {
    float4 v = make_float4(acc[i][0], acc[i][1], acc[i][2], acc[i][3]);
    *(float4*)&C[(size_t)(row0 + ty * 4 + i) * HH + col0 + tx * 4] = v;
  }
}

extern "C" void kernel_launch(void* const* d_in, const int* in_sizes, int n_in,
                              void* d_out, int out_size, void* d_ws, size_t ws_size,
                              hipStream_t stream) {
  const float* x     = (const float*)d_in[0];
  const float* c_in  = (const float*)d_in[1];
  const float* h_in  = (const float*)d_in[2];
  const float* W     = (const float*)d_in[3];
  const float* b     = (const float*)d_in[4];
  const float* Wout  = (const float*)d_in[5];
  const float* bout  = (const float*)d_in[6];
  float* out = (float*)d_out;

  float* Hh = (float*)d_ws;                       // (T+1) x H history, 33.6 MB
  float* out_tail = out + (size_t)T_STEPS * HH;   // c_last | h_last

  void* args[] = {(void*)&x, (void*)&c_in, (void*)&h_in, (void*)&W,
                  (void*)&b, (void*)&Hh, (void*)&out_tail};
  hipLaunchCooperativeKernel((void*)lstm_scan, dim3(NWG), dim3(NTHR),
                             args, 0, stream);

  const float* hs = Hh + HH;  // rows 1..T of the history
  out_gemm<<<dim3(HH / BN, T_STEPS / BM), 256, 0, stream>>>(hs, Wout, bout, out);
}

// Round 2
// 24533.612 us; speedup vs baseline: 20.6811x; 20.6811x over previous
//
#include <hip/hip_runtime.h>

#define T_STEPS 8192
#define DD 1024
#define HH 1024
#define NWG 256
#define NTHR 512
#define SCOPE_AGENT __HIP_MEMORY_SCOPE_AGENT

// XOR swizzle (float index) so the 4 segs of a wave hit distinct bank quads
// when broadcasting 16B chunks to 16 lanes each.
__device__ __forceinline__ int swz(int k) { return k ^ ((((k) >> 6) & 3) << 2); }

// Persistent scan: WG g owns h[4g..4g+4). Thread (seg=tid>>4, col=tid&15)
// covers rows k=seg*64..+64 of the 2048-long dot for z-column
// (gate=col>>2)*H + g*4 + (col&3). segs 0..15 = x-part, 16..31 = h-part.
// Weights live in LDS in a packed per-lane layout: chunk j of thread tid at
// float offset ((wave*16+j)*64 + lane)*4  -> ds_read_b128 is a contiguous
// 1KB wave read, conflict-free.
__global__ __launch_bounds__(NTHR, 1) void lstm_scan(
    const float* __restrict__ x, const float* __restrict__ c_in,
    const float* __restrict__ h_in, const float* __restrict__ W,
    const float* __restrict__ b, float* __restrict__ Hs,   // [T][H] = h_1..h_T
    float* __restrict__ hbuf,       // [2][H] coherent ping-pong
    unsigned* __restrict__ flags,   // [NWG] monotone step counters
    float* __restrict__ out_tail)   // c_last | h_last
{
  const int g = blockIdx.x, tid = threadIdx.x;
  const int lane = tid & 63, wave = tid >> 6;
  const int col = tid & 15, seg = tid >> 4;
  const int gate = col >> 2, hi = col & 3;
  const int cg = gate * HH + g * 4 + hi;

  __shared__ float Wl[32768];       // 128 KB packed weight slice
  __shared__ float xb[DD];          // swizzled x_t
  __shared__ float hb[HH];          // swizzled h_{t-1}
  __shared__ float partial[8][16];  // per-wave column partials

  // One-time weight staging: 64 strided global loads -> packed LDS.
  #pragma unroll
  for (int j = 0; j < 16; ++j) {
    float4 v;
    v.x = W[(size_t)(seg * 64 + j * 4 + 0) * (4 * HH) + cg];
    v.y = W[(size_t)(seg * 64 + j * 4 + 1) * (4 * HH) + cg];
    v.z = W[(size_t)(seg * 64 + j * 4 + 2) * (4 * HH) + cg];
    v.w = W[(size_t)(seg * 64 + j * 4 + 3) * (4 * HH) + cg];
    *(float4*)&Wl[(wave * 16 + j) * 256 + lane * 4] = v;
  }

  float c_reg = 0.f, hlast = 0.f;
  if (tid < 4) c_reg = c_in[g * 4 + tid];

  // Publish h_0 = h_in (coherent), then flag = 1.
  if (tid < 4)
    __hip_atomic_store(&hbuf[g * 4 + tid], h_in[g * 4 + tid],
                       __ATOMIC_RELAXED, SCOPE_AGENT);
  asm volatile("s_waitcnt vmcnt(0)" ::: "memory");
  if (tid == 0)
    __hip_atomic_store(&flags[g], 1u, __ATOMIC_RELAXED, SCOPE_AGENT);
  __syncthreads();  // Wl + publish done

  const bool is_x = (seg < 16);
  const int s2 = seg - 16;

  for (int t = 1; t <= T_STEPS; ++t) {
    // S0: stage x_t (plain loads, read-only input).
    {
      const float* xr = x + (size_t)(t - 1) * DD;
      xb[swz(tid)]       = xr[tid];
      xb[swz(tid + 512)] = xr[tid + 512];
    }
    __syncthreads();

    // S1: x-half dot (independent of h -> overlaps other WGs' step tail).
    if (is_x) {
      float p = 0.f;
      #pragma unroll
      for (int j = 0; j < 16; ++j) {
        const float4 wv = *(const float4*)&Wl[(wave * 16 + j) * 256 + lane * 4];
        const float4 xv = *(const float4*)&xb[(seg * 64 + j * 4) ^ ((seg & 3) << 2)];
        p = fmaf(xv.x, wv.x, p); p = fmaf(xv.y, wv.y, p);
        p = fmaf(xv.z, wv.z, p); p = fmaf(xv.w, wv.w, p);
      }
      p += __shfl_xor(p, 16);
      p += __shfl_xor(p, 32);
      if (lane < 16) partial[wave][lane] = p;
    }

    // S2: wave 0 spins until all WGs published h_{t-1} (flags >= t).
    if (wave == 0) {
      const unsigned tgt = (unsigned)t;
      for (;;) {
        const unsigned f0 = __hip_atomic_load(&flags[lane * 4 + 0], __ATOMIC_RELAXED, SCOPE_AGENT);
        const unsigned f1 = __hip_atomic_load(&flags[lane * 4 + 1], __ATOMIC_RELAXED, SCOPE_AGENT);
        const unsigned f2 = __hip_atomic_load(&flags[lane * 4 + 2], __ATOMIC_RELAXED, SCOPE_AGENT);
        const unsigned f3 = __hip_atomic_load(&flags[lane * 4 + 3], __ATOMIC_RELAXED, SCOPE_AGENT);
        if (__all(f0 >= tgt && f1 >= tgt && f2 >= tgt && f3 >= tgt)) break;
        __builtin_amdgcn_s_sleep(1);
      }
    }
    __syncthreads();

    // S3: stage h_{t-1} via coherent loads (bypass stale L1/L2).
    {
      const float* hr = hbuf + ((t - 1) & 1) * HH;
      hb[swz(tid)]       = __hip_atomic_load(&hr[tid],       __ATOMIC_RELAXED, SCOPE_AGENT);
      hb[swz(tid + 512)] = __hip_atomic_load(&hr[tid + 512], __ATOMIC_RELAXED, SCOPE_AGENT);
    }
    __syncthreads();

    // S4: h-half dot.
    if (!is_x) {
      float q = 0.f;
      #pragma unroll
      for (int j = 0; j < 16; ++j) {
        const float4 wv = *(const float4*)&Wl[(wave * 16 + j) * 256 + lane * 4];
        const float4 hv = *(const float4*)&hb[(s2 * 64 + j * 4) ^ ((s2 & 3) << 2)];
        q = fmaf(hv.x, wv.x, q); q = fmaf(hv.y, wv.y, q);
        q = fmaf(hv.z, wv.z, q); q = fmaf(hv.w, wv.w, q);
      }
      q += __shfl_xor(q, 16);
      q += __shfl_xor(q, 32);
      if (lane < 16) partial[wave][lane] = q;
    }
    __syncthreads();

    // S5: wave 0 reduces, applies gates, publishes h_t.
    if (wave == 0) {
      float zsum = b[((lane & 15) >> 2) * HH + g * 4 + (lane & 3)];
      #pragma unroll
      for (int wv = 0; wv < 8; ++wv) zsum += partial[wv][lane & 15];
      const float zi = __shfl(zsum, tid);       // lanes 0..3 gather their 4 gates
      const float zj = __shfl(zsum, tid + 4);
      const float zf = __shfl(zsum, tid + 8);
      const float zo = __shfl(zsum, tid + 12);
      if (tid < 4) {
        const float fg = 1.f / (1.f + __expf(-(zf + 1.0f)));  // FORGET_BIAS
        const float ig = 1.f / (1.f + __expf(-zi));
        const float nc = c_reg * fg + ig * tanhf(zj);
        const float nh = tanhf(nc) * (1.f / (1.f + __expf(-zo)));
        c_reg = nc; hlast = nh;
        __hip_atomic_store(&hbuf[(t & 1) * HH + g * 4 + tid], nh,
                           __ATOMIC_RELAXED, SCOPE_AGENT);
        Hs[(size_t)(t - 1) * HH + g * 4 + tid] = nh;  // history for out_gemm
      }
      asm volatile("s_waitcnt vmcnt(0)" ::: "memory");
      if (tid == 0)
        __hip_atomic_store(&flags[g], (unsigned)(t + 1), __ATOMIC_RELAXED, SCOPE_AGENT);
    }
  }

  if (tid < 4) {
    out_tail[g * 4 + tid]      = c_reg;   // c_last
    out_tail[HH + g * 4 + tid] = hlast;   // h_last
  }
}

// output = hs @ W_out + b_out. fp32 tiled GEMM, 64x64 tile, 4x4/thread.
#define BM 64
#define BN 64
#define BK 16
__global__ __launch_bounds__(256, 2) void out_gemm(
    const float* __restrict__ A,    // hs [8192][1024]
    const float* __restrict__ Bw,   // W_out [1024][1024]
    const float* __restrict__ bias,
    float* __restrict__ C)          // [8192][1024]
{
  __shared__ float As[BM][BK];
  __shared__ float Bs[BK][BN];
  const int tid = threadIdx.x;
  const int row0 = blockIdx.y * BM, col0 = blockIdx.x * BN;
  const int tx = tid & 15, ty = tid >> 4;

  float acc[4][4];
  #pragma unroll
  for (int j = 0; j < 4; ++j) {
    const float bv = bias[col0 + tx * 4 + j];
    #pragma unroll
    for (int i = 0; i < 4; ++i) acc[i][j] = bv;
  }

  for (int k0 = 0; k0 < HH; k0 += BK) {
    {
      const int r = tid >> 2, c = (tid & 3) * 4;
      const float4 va = *(const float4*)&A[(size_t)(row0 + r) * HH + k0 + c];
      As[r][c] = va.x; As[r][c + 1] = va.y; As[r][c + 2] = va.z; As[r][c + 3] = va.w;
      const int rb = tid >> 4, cb = (tid & 15) * 4;
      *(float4*)&Bs[rb][cb] = *(const float4*)&Bw[(size_t)(k0 + rb) * HH + col0 + cb];
    }
    __syncthreads();
    #pragma unroll
    for (int kk = 0; kk < BK; ++kk) {
      float a[4], bv[4];
      #pragma unroll
      for (int i = 0; i < 4; ++i) a[i] = As[ty * 4 + i][kk];
      #pragma unroll
      for (int j = 0; j < 4; ++j) bv[j] = Bs[kk][tx * 4 + j];
      #pragma unroll
      for (int i = 0; i < 4; ++i)
        #pragma unroll
        for (int j = 0; j < 4; ++j)
          acc[i][j] = fmaf(a[i], bv[j], acc[i][j]);
    }
    __syncthreads();
  }

  #pragma unroll
  for (int i = 0; i < 4; ++i) {
    float4 v = make_float4(acc[i][0], acc[i][1], acc[i][2], acc[i][3]);
    *(float4*)&C[(size_t)(row0 + ty * 4 + i) * HH + col0 + tx * 4] = v;
  }
}

extern "C" void kernel_launch(void* const* d_in, const int* in_sizes, int n_in,
                              void* d_out, int out_size, void* d_ws, size_t ws_size,
                              hipStream_t stream) {
  const float* x    = (const float*)d_in[0];
  const float* c_in = (const float*)d_in[1];
  const float* h_in = (const float*)d_in[2];
  const float* W    = (const float*)d_in[3];
  const float* b    = (const float*)d_in[4];
  const float* Wout = (const float*)d_in[5];
  const float* bout = (const float*)d_in[6];
  float* out = (float*)d_out;

  // ws layout: Hs [T*H floats] | hbuf [2*H floats] | flags [NWG u32]
  float* Hs = (float*)d_ws;
  float* hbuf = Hs + (size_t)T_STEPS * HH;
  unsigned* flags = (unsigned*)(hbuf + 2 * HH);
  float* out_tail = out + (size_t)T_STEPS * HH;

  // Deterministic barrier state on every (graph-replayed) launch.
  hipMemsetAsync(flags, 0, NWG * sizeof(unsigned), stream);

  void* args[] = {(void*)&x, (void*)&c_in, (void*)&h_in, (void*)&W, (void*)&b,
                  (void*)&Hs, (void*)&hbuf, (void*)&flags, (void*)&out_tail};
  hipLaunchCooperativeKernel((void*)lstm_scan, dim3(NWG), dim3(NTHR),
                             args, 0, stream);

  out_gemm<<<dim3(HH / BN, T_STEPS / BM), 256, 0, stream>>>(Hs, Wout, bout, out);
}

// Round 3
// 16254.692 us; speedup vs baseline: 31.2144x; 1.5093x over previous
//
#include <hip/hip_runtime.h>

#define T_STEPS 8192
#define DD 1024
#define HH 1024
#define NWG 256
#define NTHR 512
#define SCOPE_AGENT __HIP_MEMORY_SCOPE_AGENT
typedef unsigned long long u64;

// XOR swizzle (float index) so the 4 segs of a wave hit distinct bank quads
// when broadcasting 16B chunks to 16 lanes each.
__device__ __forceinline__ int swz(int k) { return k ^ ((((k) >> 6) & 3) << 2); }

__device__ __forceinline__ float fsig(float v) {
  return 1.f / (1.f + __expf(-v));
}
__device__ __forceinline__ float ftanh(float v) {
  return 2.f / (1.f + __expf(-2.f * v)) - 1.f;
}

// Persistent scan: WG g owns h[4g..4g+4). Thread (seg=tid>>4, col=tid&15)
// covers rows k=seg*64..+64 of the 2048-long dot for z-column
// (gate=col>>2)*H + g*4 + (col&3). segs 0..15 = x-part, 16..31 = h-part.
// h is published as 64-bit (tag<<32 | float_bits) atoms, ping-ponged over 2
// slots; consumers spin directly on the tagged data (no separate flag, no
// producer-side fence: tag and value travel in the same atom).
__global__ __launch_bounds__(NTHR, 1) void lstm_scan(
    const float* __restrict__ x, const float* __restrict__ c_in,
    const float* __restrict__ h_in, const float* __restrict__ W,
    const float* __restrict__ b, float* __restrict__ Hs,  // [T][H] = h_1..h_T
    u64* __restrict__ hbuf,         // [2][H] tagged ping-pong (memset 0)
    float* __restrict__ out_tail)   // c_last | h_last
{
  const int g = blockIdx.x, tid = threadIdx.x;
  const int lane = tid & 63, wave = tid >> 6;
  const int col = tid & 15, seg = tid >> 4;
  const int gate = col >> 2, hi = col & 3;
  const int cg = gate * HH + g * 4 + hi;

  __shared__ float Wl[32768];       // 128 KB packed weight slice
  __shared__ float xb[DD];          // swizzled x_t
  __shared__ float hb[HH];          // swizzled h_{t-1}
  __shared__ float partial[8][16];  // per-wave column partials

  float c_reg = 0.f, hlast = 0.f;

  // Publish h_0 immediately (slot 0, tag 1) so consumers' first polls hit.
  if (tid < 4) {
    const float h0 = h_in[g * 4 + tid];
    c_reg = c_in[g * 4 + tid];
    const u64 pv = ((u64)1u << 32) | (u64)__float_as_uint(h0);
    __hip_atomic_store(&hbuf[g * 4 + tid], pv, __ATOMIC_RELAXED, SCOPE_AGENT);
  }

  // One-time weight staging: 64 strided global loads -> packed LDS.
  #pragma unroll
  for (int j = 0; j < 16; ++j) {
    float4 v;
    v.x = W[(size_t)(seg * 64 + j * 4 + 0) * (4 * HH) + cg];
    v.y = W[(size_t)(seg * 64 + j * 4 + 1) * (4 * HH) + cg];
    v.z = W[(size_t)(seg * 64 + j * 4 + 2) * (4 * HH) + cg];
    v.w = W[(size_t)(seg * 64 + j * 4 + 3) * (4 * HH) + cg];
    *(float4*)&Wl[(wave * 16 + j) * 256 + lane * 4] = v;
  }

  // Loop-invariant bias for this thread's column (used by wave 0 only).
  const float bias_reg = b[((lane & 15) >> 2) * HH + g * 4 + (lane & 3)];

  __syncthreads();  // Wl ready

  const bool is_x = (seg < 16);
  const int s2 = seg - 16;

  for (int t = 1; t <= T_STEPS; ++t) {
    // A: stage x_t (off the h critical path).
    {
      const float* xr = x + (size_t)(t - 1) * DD;
      xb[swz(tid)]       = xr[tid];
      xb[swz(tid + 512)] = xr[tid + 512];
    }
    __syncthreads();  // xb ready; also: prev-step partial reads done

    // B: x-half dot (overlaps other WGs' publish latency).
    if (is_x) {
      float p = 0.f;
      #pragma unroll
      for (int j = 0; j < 16; ++j) {
        const float4 wv = *(const float4*)&Wl[(wave * 16 + j) * 256 + lane * 4];
        const float4 xv = *(const float4*)&xb[(seg * 64 + j * 4) ^ ((seg & 3) << 2)];
        p = fmaf(xv.x, wv.x, p); p = fmaf(xv.y, wv.y, p);
        p = fmaf(xv.z, wv.z, p); p = fmaf(xv.w, wv.w, p);
      }
      p += __shfl_xor(p, 16);
      p += __shfl_xor(p, 32);
      if (lane < 16) partial[wave][lane] = p;
    }

    // C: every thread spins on its own 2 tagged h atoms (data + readiness in
    // one load). Tag >= t means h_{t-1} is present.
    {
      const u64* hp = hbuf + ((t - 1) & 1) * HH;
      u64 v0 = __hip_atomic_load(&hp[tid],       __ATOMIC_RELAXED, SCOPE_AGENT);
      u64 v1 = __hip_atomic_load(&hp[tid + 512], __ATOMIC_RELAXED, SCOPE_AGENT);
      bool r0 = (unsigned)(v0 >> 32) >= (unsigned)t;
      bool r1 = (unsigned)(v1 >> 32) >= (unsigned)t;
      while (!(r0 && r1)) {
        __builtin_amdgcn_s_sleep(1);
        if (!r0) {
          v0 = __hip_atomic_load(&hp[tid], __ATOMIC_RELAXED, SCOPE_AGENT);
          r0 = (unsigned)(v0 >> 32) >= (unsigned)t;
        }
        if (!r1) {
          v1 = __hip_atomic_load(&hp[tid + 512], __ATOMIC_RELAXED, SCOPE_AGENT);
          r1 = (unsigned)(v1 >> 32) >= (unsigned)t;
        }
      }
      hb[swz(tid)]       = __uint_as_float((unsigned)v0);
      hb[swz(tid + 512)] = __uint_as_float((unsigned)v1);
    }
    __syncthreads();  // hb ready + x-partials written

    // D: h-half dot.
    if (!is_x) {
      float q = 0.f;
      #pragma unroll
      for (int j = 0; j < 16; ++j) {
        const float4 wv = *(const float4*)&Wl[(wave * 16 + j) * 256 + lane * 4];
        const float4 hv = *(const float4*)&hb[(s2 * 64 + j * 4) ^ ((s2 & 3) << 2)];
        q = fmaf(hv.x, wv.x, q); q = fmaf(hv.y, wv.y, q);
        q = fmaf(hv.z, wv.z, q); q = fmaf(hv.w, wv.w, q);
      }
      q += __shfl_xor(q, 16);
      q += __shfl_xor(q, 32);
      if (lane < 16) partial[wave][lane] = q;
    }
    __syncthreads();  // all partials ready

    // E: wave 0 reduces, applies gates, publishes tagged h_t.
    if (wave == 0) {
      float zsum = bias_reg;
      #pragma unroll
      for (int wv = 0; wv < 8; ++wv) zsum += partial[wv][lane & 15];
      const float zi = __shfl(zsum, tid);       // lanes 0..3 gather their gates
      const float zj = __shfl(zsum, tid + 4);
      const float zf = __shfl(zsum, tid + 8);
      const float zo = __shfl(zsum, tid + 12);
      if (tid < 4) {
        const float fg = fsig(zf + 1.0f);       // FORGET_BIAS
        const float nc = c_reg * fg + fsig(zi) * ftanh(zj);
        const float nh = ftanh(nc) * fsig(zo);
        c_reg = nc; hlast = nh;
        const u64 pv = ((u64)(unsigned)(t + 1) << 32) | (u64)__float_as_uint(nh);
        __hip_atomic_store(&hbuf[(t & 1) * HH + g * 4 + tid], pv,
                           __ATOMIC_RELAXED, SCOPE_AGENT);
        Hs[(size_t)(t - 1) * HH + g * 4 + tid] = nh;  // fire-and-forget
      }
    }
  }

  if (tid < 4) {
    out_tail[g * 4 + tid]      = c_reg;   // c_last
    out_tail[HH + g * 4 + tid] = hlast;   // h_last
  }
}

// output = hs @ W_out + b_out. fp32 tiled GEMM, 64x64 tile, 4x4/thread.
#define BM 64
#define BN 64
#define BK 16
__global__ __launch_bounds__(256, 2) void out_gemm(
    const float* __restrict__ A,    // hs [8192][1024]
    const float* __restrict__ Bw,   // W_out [1024][1024]
    const float* __restrict__ bias,
    float* __restrict__ C)          // [8192][1024]
{
  __shared__ float As[BM][BK];
  __shared__ float Bs[BK][BN];
  const int tid = threadIdx.x;
  const int row0 = blockIdx.y * BM, col0 = blockIdx.x * BN;
  const int tx = tid & 15, ty = tid >> 4;

  float acc[4][4];
  #pragma unroll
  for (int j = 0; j < 4; ++j) {
    const float bv = bias[col0 + tx * 4 + j];
    #pragma unroll
    for (int i = 0; i < 4; ++i) acc[i][j] = bv;
  }

  for (int k0 = 0; k0 < HH; k0 += BK) {
    {
      const int r = tid >> 2, c = (tid & 3) * 4;
      const float4 va = *(const float4*)&A[(size_t)(row0 + r) * HH + k0 + c];
      As[r][c] = va.x; As[r][c + 1] = va.y; As[r][c + 2] = va.z; As[r][c + 3] = va.w;
      const int rb = tid >> 4, cb = (tid & 15) * 4;
      *(float4*)&Bs[rb][cb] = *(const float4*)&Bw[(size_t)(k0 + rb) * HH + col0 + cb];
    }
    __syncthreads();
    #pragma unroll
    for (int kk = 0; kk < BK; ++kk) {
      float a[4], bv[4];
      #pragma unroll
      for (int i = 0; i < 4; ++i) a[i] = As[ty * 4 + i][kk];
      #pragma unroll
      for (int j = 0; j < 4; ++j) bv[j] = Bs[kk][tx * 4 + j];
      #pragma unroll
      for (int i = 0; i < 4; ++i)
        #pragma unroll
        for (int j = 0; j < 4; ++j)
          acc[i][j] = fmaf(a[i], bv[j], acc[i][j]);
    }
    __syncthreads();
  }

  #pragma unroll
  for (int i = 0; i < 4; ++i) {
    float4 v = make_float4(acc[i][0], acc[i][1], acc[i][2], acc[i][3]);
    *(float4*)&C[(size_t)(row0 + ty * 4 + i) * HH + col0 + tx * 4] = v;
  }
}

extern "C" void kernel_launch(void* const* d_in, const int* in_sizes, int n_in,
                              void* d_out, int out_size, void* d_ws, size_t ws_size,
                              hipStream_t stream) {
  const float* x    = (const float*)d_in[0];
  const float* c_in = (const float*)d_in[1];
  const float* h_in = (const float*)d_in[2];
  const float* W    = (const float*)d_in[3];
  const float* b    = (const float*)d_in[4];
  const float* Wout = (const float*)d_in[5];
  const float* bout = (const float*)d_in[6];
  float* out = (float*)d_out;

  // ws layout: hbuf [2*H u64, 16KB] | Hs [T*H floats, 32MB]
  u64* hbuf = (u64*)d_ws;
  float* Hs = (float*)(hbuf + 2 * HH);
  float* out_tail = out + (size_t)T_STEPS * HH;

  // Tags must start at 0 every launch (graph replays reuse ws).
  hipMemsetAsync(hbuf, 0, 2 * HH * sizeof(u64), stream);

  void* args[] = {(void*)&x, (void*)&c_in, (void*)&h_in, (void*)&W, (void*)&b,
                  (void*)&Hs, (void*)&hbuf, (void*)&out_tail};
  hipLaunchCooperativeKernel((void*)lstm_scan, dim3(NWG), dim3(NTHR),
                             args, 0, stream);

  out_gemm<<<dim3(HH / BN, T_STEPS / BM), 256, 0, stream>>>(Hs, Wout, bout, out);
}